// Round 9
// baseline (528.130 us; speedup 1.0000x reference)
//
#include <hip/hip_runtime.h>
#include <stdint.h>

// Problem constants (B=2, Nr=40962, in_ch=128, out_ch=64). FP32 I/O.
#define NR     40962
#define NH     163842      // 4*NR-6
#define NR7    286734      // NR*7
#define M_UP   40962
#define M_CV   327684      // B*NH
#define BN_EPS 1e-5f
#define SLOPE  0.2f

typedef __attribute__((ext_vector_type(8))) short  short8;
typedef __attribute__((ext_vector_type(4))) float  f32x4;
typedef unsigned short ushort_t;

__device__ __forceinline__ ushort_t f2bf(float f) {
  union { float f; uint32_t u; } v; v.f = f;
  uint32_t r = v.u + 0x7fffu + ((v.u >> 16) & 1u);  // RNE
  return (ushort_t)(r >> 16);
}
__device__ __forceinline__ float bf2f(ushort_t h) {
  union { uint32_t u; float f; } v; v.u = ((uint32_t)h) << 16;
  return v.f;
}
__device__ __forceinline__ int clampi(int v, int hi) {
  v = v < 0 ? 0 : v;
  return v >= hi ? hi - 1 : v;
}

// ---------------------------------------------------------------------------
// Gather-GEMM, 256-row tile, 8 waves (512 thr), 32 rows/wave.
// MODE 1/2 (conv1/conv2): R6 structure UNCHANGED — best measured (conv1
//   122 µs across 6 structural variants = random-gather fabric plateau).
//   A: global->VGPR gather (16B/lane = exact MFMA fragment), 4-slot ring,
//   barrier-free K-loop, compiler-counted per-wave vmcnt. B: staged once
//   per stage, rows padded to KHALF+8 (912B stride, balanced bank groups).
// MODE 0 (up-GEMM): NEW — full A (K=128) held in registers, read fp32 ONCE
//   (in-register cvt; kills both the cvt_bf pre-pass AND the 7x n-tile
//   A re-read of R8). Internal loop over all 7 n-tiles: stage B tile
//   (64x136 bf16 = 17KB LDS), compute, write tile.
// Register plan: ~64 arch VGPR + AGPR parking — no scratch.
// WRITE_SIZE ~53MB (conv1) is the spill tripwire.
// FSTATS: fused per-channel sum/sumsq -> statsPart[16 slices][128].
// ---------------------------------------------------------------------------
template<int MODE, bool FSTATS>
__global__ __launch_bounds__(512, 2) void gemm_conv(
    const ushort_t* __restrict__ Asrc,   // MODE0: actually const float*
    const int*      __restrict__ neigh,
    const float*    __restrict__ Wf,     // fp32 [K][NW]
    const float*    __restrict__ bias,
    void*           __restrict__ OutV,
    float*          __restrict__ statsPart,
    int M, int NW)
{
  constexpr int KHALF = (MODE == 0) ? 128 : 448;
  constexpr int NSTAGE = (MODE == 1) ? 2 : 1;
  constexpr int NCH   = (MODE == 1) ? 14 : 7;   // conv modes only
  constexpr int RS = KHALF + 8;          // padded row stride (elems)
  __shared__ __align__(16) ushort_t Bs[64 * RS];

  const int tid  = threadIdx.x;
  const int wv   = tid >> 6;             // 0..7
  const int lane = tid & 63;
  const int r16  = lane & 15;
  const int q    = lane >> 4;
  const int mTile = blockIdx.y * 256;
  constexpr int ROWE = (MODE == 2) ? 64 : 128;   // A row length (elems)

  // ---------------- MODE 0: dense up-GEMM, all 7 n-tiles per block --------
  if constexpr (MODE == 0) {
    const float* Af = (const float*)Asrc;
    short8 aregF[2][2][2];               // [ch][rowgroup][ks], full K=128
#pragma unroll
    for (int ch = 0; ch < 2; ++ch) {
#pragma unroll
      for (int rg = 0; rg < 2; ++rg) {
        int r = mTile + wv * 32 + rg * 16 + r16;
        if (r >= M) r = M - 1;
        const float* base = Af + (size_t)r * 128 + ch * 64 + q * 8;
        const f32x4 a0 = *(const f32x4*)(base);
        const f32x4 a1 = *(const f32x4*)(base + 4);
        const f32x4 b0 = *(const f32x4*)(base + 32);
        const f32x4 b1 = *(const f32x4*)(base + 36);
        short8 v0, v1;
#pragma unroll
        for (int u = 0; u < 4; ++u) {
          v0[u]     = (short)f2bf(a0[u]);
          v0[u + 4] = (short)f2bf(a1[u]);
          v1[u]     = (short)f2bf(b0[u]);
          v1[u + 4] = (short)f2bf(b1[u]);
        }
        aregF[ch][rg][0] = v0;
        aregF[ch][rg][1] = v1;
      }
    }

    for (int nt = 0; nt < 7; ++nt) {
      const int nTile = nt * 64;
      if (nt > 0) __syncthreads();       // all reads of previous Bs done
      { // stage B tile: K=128 x 64 cols; thread n=tid&63, 2 slots of 8 k.
        const int n   = tid & 63;
        const int sub = tid >> 6;
#pragma unroll
        for (int v = 0; v < 2; ++v) {
          const int slot = sub + v * 8;  // 0..15
          const int kg = slot * 8;
          float f[8];
#pragma unroll
          for (int u = 0; u < 8; ++u)
            f[u] = Wf[(size_t)(kg + u) * NW + nTile + n];
          short8 o;
#pragma unroll
          for (int u = 0; u < 8; ++u) o[u] = (short)f2bf(f[u]);
          *(short8*)&Bs[n * RS + slot * 8] = o;
        }
      }
      __syncthreads();

      f32x4 acc[2][4];
#pragma unroll
      for (int a = 0; a < 2; ++a)
#pragma unroll
        for (int i = 0; i < 4; ++i) acc[a][i] = (f32x4){0.f, 0.f, 0.f, 0.f};
#pragma unroll
      for (int ch = 0; ch < 2; ++ch) {
#pragma unroll
        for (int ks = 0; ks < 2; ++ks) {
          const int kk = ch * 64 + ks * 32 + q * 8;
#pragma unroll
          for (int ct = 0; ct < 4; ++ct) {
            const short8 b = *(const short8*)&Bs[(ct * 16 + r16) * RS + kk];
#pragma unroll
            for (int rg = 0; rg < 2; ++rg)
              acc[rg][ct] = __builtin_amdgcn_mfma_f32_16x16x32_bf16(
                  aregF[ch][rg][ks], b, acc[rg][ct], 0, 0, 0);
          }
        }
      }
      // write tile nt
#pragma unroll
      for (int ct = 0; ct < 4; ++ct) {
        const int colg = nTile + ct * 16 + r16;
        const float bv = bias[colg];
#pragma unroll
        for (int rg = 0; rg < 2; ++rg) {
#pragma unroll
          for (int i = 0; i < 4; ++i) {
            const int rowg = mTile + wv * 32 + rg * 16 + q * 4 + i;
            if (rowg < M)
              ((ushort_t*)OutV)[(size_t)rowg * NW + colg] =
                  f2bf(acc[rg][ct][i] + bv);
          }
        }
      }
    }
    return;
  }

  // ---------------- MODE 1/2: gather conv (R6 structure, unchanged) -------
  const int nTile = blockIdx.x * 64;

  int idx[2][7];
#pragma unroll
  for (int rg = 0; rg < 2; ++rg) {
    int r = mTile + wv * 32 + rg * 16 + r16;
    if (r >= M) r = M - 1;
    const int gb = (r >= NH) ? 1 : 0;
    const int gn = r - gb * NH;
#pragma unroll
    for (int j = 0; j < 7; ++j)
      idx[rg][j] = gb * NH + clampi(neigh[gn * 7 + j], NH);
  }

  f32x4 acc[2][4];
#pragma unroll
  for (int a = 0; a < 2; ++a)
#pragma unroll
    for (int i = 0; i < 4; ++i) acc[a][i] = (f32x4){0.f, 0.f, 0.f, 0.f};

  short8 areg[4][2][2];   // [ringslot][rowgroup][ks] — statically indexed

  auto loadA = [&](int slot, int ch) {
    const int j  = (MODE == 1) ? (ch >> 1) : ch;
    const int cb = (MODE == 1) ? ((ch & 1) << 6) : 0;
#pragma unroll
    for (int rg = 0; rg < 2; ++rg) {
      const ushort_t* base = Asrc + (size_t)idx[rg][j] * ROWE + cb + q * 8;
      areg[slot][rg][0] = *(const short8*)(base);
      areg[slot][rg][1] = *(const short8*)(base + 32);
    }
  };

  auto stageB = [&](int s) {
    const int n   = tid & 63;
    const int sub = tid >> 6;            // 0..7
    for (int slot = sub; slot < KHALF / 8; slot += 8) {
      const int kg = s * KHALF + slot * 8;
      float f[8];
#pragma unroll
      for (int u = 0; u < 8; ++u)
        f[u] = Wf[(size_t)(kg + u) * NW + nTile + n];
      short8 v;
#pragma unroll
      for (int u = 0; u < 8; ++u) v[u] = (short)f2bf(f[u]);
      *(short8*)&Bs[n * RS + slot * 8] = v;
    }
  };

  auto compute = [&](int slot, int chLoc) {
#pragma unroll
    for (int ks = 0; ks < 2; ++ks) {
      const int kk = chLoc * 64 + ks * 32 + q * 8;
#pragma unroll
      for (int ct = 0; ct < 4; ++ct) {
        const short8 b = *(const short8*)&Bs[(ct * 16 + r16) * RS + kk];
#pragma unroll
        for (int rg = 0; rg < 2; ++rg)
          acc[rg][ct] = __builtin_amdgcn_mfma_f32_16x16x32_bf16(
              areg[slot][rg][ks], b, acc[rg][ct], 0, 0, 0);
      }
    }
  };

  // Prologue: 3 chunks of A in flight under the whole B-staging.
  loadA(0, 0);
  loadA(1, 1);
  loadA(2, 2);
  stageB(0);
  __syncthreads();

#pragma unroll
  for (int s = 0; s < NSTAGE; ++s) {
    if (s > 0) {
      __syncthreads();    // all waves done reading previous stage's Bs
      stageB(s);
      __syncthreads();
    }
#pragma unroll
    for (int chLoc = 0; chLoc < KHALF / 64; ++chLoc) {
      const int ch = s * (KHALF / 64) + chLoc;
      if (ch + 3 < NCH) loadA((ch + 3) % 4, ch + 3);
      compute(ch % 4, chLoc);
    }
  }

  // epilogue: C/D layout col=lane&15, row=(lane>>4)*4+reg
  float s1a[4] = {0.f, 0.f, 0.f, 0.f};
  float s2a[4] = {0.f, 0.f, 0.f, 0.f};
#pragma unroll
  for (int ct = 0; ct < 4; ++ct) {
    const int colg = nTile + ct * 16 + r16;
    const float bv = bias[colg];
#pragma unroll
    for (int rg = 0; rg < 2; ++rg) {
#pragma unroll
      for (int i = 0; i < 4; ++i) {
        const int rowg = mTile + wv * 32 + rg * 16 + q * 4 + i;
        const float y = acc[rg][ct][i] + bv;
        if (rowg < M) {
          if constexpr (MODE == 2)
            ((float*)OutV)[(size_t)rowg * NW + colg] = y;
          else
            ((ushort_t*)OutV)[(size_t)rowg * NW + colg] = f2bf(y);
          if constexpr (FSTATS) { s1a[ct] += y; s2a[ct] += y * y; }
        }
      }
    }
  }

  if constexpr (FSTATS) {
    __syncthreads();                     // all Bs reads done; reuse as scratch
    float* Sred  = (float*)&Bs[0];       // [8 waves][64 ch]
    float* S2red = Sred + 512;
#pragma unroll
    for (int ct = 0; ct < 4; ++ct) {
      float v = s1a[ct], w = s2a[ct];
      v += __shfl_xor(v, 16, 64); v += __shfl_xor(v, 32, 64);
      w += __shfl_xor(w, 16, 64); w += __shfl_xor(w, 32, 64);
      if (q == 0) {
        Sred[wv * 64 + ct * 16 + r16]  = v;
        S2red[wv * 64 + ct * 16 + r16] = w;
      }
    }
    __syncthreads();
    if (tid < 64) {
      float v = 0.f, w = 0.f;
#pragma unroll
      for (int i = 0; i < 8; ++i) {
        v += Sred[i * 64 + tid];
        w += S2red[i * 64 + tid];
      }
      float* p = statsPart + (size_t)(blockIdx.y & 15) * 128;
      atomicAdd(&p[tid], v);
      atomicAdd(&p[64 + tid], w);
    }
  }
}

// ---------------------------------------------------------------------------
// Per batch: units [0, NH*8) build xup into LOW 64 channels of xcat rows;
// units [NH*8, NH*16) convert x2 (this batch) into HIGH 64 channels.
// ---------------------------------------------------------------------------
__global__ __launch_bounds__(256) void build_xup_x2_kernel(
    const ushort_t* __restrict__ h, const int* __restrict__ top,
    const int* __restrict__ down, const float* __restrict__ x2b,
    ushort_t* __restrict__ xcatB, long long total)
{
  const long long gid = (long long)blockIdx.x * 256 + threadIdx.x;
  if (gid >= total) return;
  if (gid < (long long)NH * 8) {
    const int n  = (int)(gid >> 3);
    const int c0 = (int)(gid & 7) * 8;
    short8 v;
    if (n < NR) {
      const int idx = clampi(top[n], NR7);
      v = *(const short8*)(h + (size_t)idx * 64 + c0);
    } else {
      const int d  = n - NR;
      const int i0 = clampi(down[d * 2], NR7);
      const int i1 = clampi(down[d * 2 + 1], NR7);
      short8 u0 = *(const short8*)(h + (size_t)i0 * 64 + c0);
      short8 u1 = *(const short8*)(h + (size_t)i1 * 64 + c0);
#pragma unroll
      for (int i = 0; i < 8; ++i)
        v[i] = (short)f2bf(0.5f * (bf2f((ushort_t)u0[i]) + bf2f((ushort_t)u1[i])));
    }
    *(short8*)(xcatB + (size_t)n * 128 + c0) = v;
  } else {
    const long long g2 = gid - (long long)NH * 8;
    const int n  = (int)(g2 >> 3);
    const int c0 = (int)(g2 & 7) * 8;
    const f32x4 f0 = *(const f32x4*)(x2b + (size_t)n * 64 + c0);
    const f32x4 f1 = *(const f32x4*)(x2b + (size_t)n * 64 + c0 + 4);
    short8 v;
#pragma unroll
    for (int i = 0; i < 4; ++i) {
      v[i]     = (short)f2bf(f0[i]);
      v[i + 4] = (short)f2bf(f1[i]);
    }
    *(short8*)(xcatB + (size_t)n * 128 + 64 + c0) = v;
  }
}

__global__ __launch_bounds__(256) void zero_kernel(float* __restrict__ p, int n) {
  const int gid = blockIdx.x * 256 + threadIdx.x;
  if (gid < n) p[gid] = 0.f;
}

// Fallback stats over fp32 buffer -> 16 partial slices
__global__ __launch_bounds__(256) void stats_f32_kernel(
    const float* __restrict__ buf, float* __restrict__ part, int rows)
{
  const int tid = threadIdx.x;
  const int c   = tid & 63;
  const int rl  = tid >> 6;
  float s = 0.f, s2 = 0.f;
  for (int r = blockIdx.x * 4 + rl; r < rows; r += gridDim.x * 4) {
    const float v = buf[(size_t)r * 64 + c];
    s += v; s2 += v * v;
  }
  __shared__ float sh[2][256];
  sh[0][tid] = s; sh[1][tid] = s2;
  __syncthreads();
  if (tid < 64) {
#pragma unroll
    for (int i = 1; i < 4; ++i) { s += sh[0][tid + 64 * i]; s2 += sh[1][tid + 64 * i]; }
    float* p = part + (size_t)(blockIdx.x & 15) * 128;
    atomicAdd(&p[c], s);
    atomicAdd(&p[64 + c], s2);
  }
}

// Fallback stats over bf16 buffer -> 16 partial slices
__global__ __launch_bounds__(256) void stats_bf16_kernel(
    const ushort_t* __restrict__ buf, float* __restrict__ part, int rows)
{
  const int tid = threadIdx.x;
  const int c   = tid & 63;
  const int rl  = tid >> 6;
  float s = 0.f, s2 = 0.f;
  for (int r = blockIdx.x * 4 + rl; r < rows; r += gridDim.x * 4) {
    const float v = bf2f(buf[(size_t)r * 64 + c]);
    s += v; s2 += v * v;
  }
  __shared__ float sh[2][256];
  sh[0][tid] = s; sh[1][tid] = s2;
  __syncthreads();
  if (tid < 64) {
#pragma unroll
    for (int i = 1; i < 4; ++i) { s += sh[0][tid + 64 * i]; s2 += sh[1][tid + 64 * i]; }
    float* p = part + (size_t)(blockIdx.x & 15) * 128;
    atomicAdd(&p[c], s);
    atomicAdd(&p[64 + c], s2);
  }
}

// Reduce 16 partial slices -> final [sc[64] | sh[64]] at part+2048
__global__ void finalize_kernel(float* __restrict__ part,
                                const float* __restrict__ gamma,
                                const float* __restrict__ beta)
{
  const int c = threadIdx.x;  // 64
  float s = 0.f, s2 = 0.f;
  for (int i = 0; i < 16; ++i) { s += part[i * 128 + c]; s2 += part[i * 128 + 64 + c]; }
  const float invN = 1.0f / (float)M_CV;
  const float mean = s * invN;
  float var = fmaxf(s2 * invN - mean * mean, 0.f);
  const float sc = gamma[c] * rsqrtf(var + BN_EPS);
  float* fin = part + 2048;
  fin[c] = sc;
  fin[64 + c] = beta[c] - mean * sc;
}

// In-place y = lrelu(v*sc[c] + sh[c]); fin = [sc[64] | sh[64]]
template<bool F32>
__global__ __launch_bounds__(256) void bnl_kernel(
    void* __restrict__ bufV, const float* __restrict__ fin, long long nvec)
{
  const long long gid = (long long)blockIdx.x * 256 + threadIdx.x;
  if (gid >= nvec) return;
  if constexpr (F32) {
    float* buf = (float*)bufV;
    const int c0 = (int)((gid * 4) & 63);
    f32x4 v = *(f32x4*)(buf + gid * 4);
#pragma unroll
    for (int i = 0; i < 4; ++i) {
      const float y = v[i] * fin[c0 + i] + fin[64 + c0 + i];
      v[i] = (y >= 0.f) ? y : SLOPE * y;
    }
    *(f32x4*)(buf + gid * 4) = v;
  } else {
    ushort_t* buf = (ushort_t*)bufV;
    const int c0 = (int)((gid * 8) & 63);
    short8 v = *(short8*)(buf + gid * 8);
#pragma unroll
    for (int i = 0; i < 8; ++i) {
      float y = bf2f((ushort_t)v[i]) * fin[c0 + i] + fin[64 + c0 + i];
      y = (y >= 0.f) ? y : SLOPE * y;
      v[i] = (short)f2bf(y);
    }
    *(short8*)(buf + gid * 8) = v;
  }
}

// ---------------------------------------------------------------------------
extern "C" void kernel_launch(void* const* d_in, const int* in_sizes, int n_in,
                              void* d_out, int out_size, void* d_ws, size_t ws_size,
                              hipStream_t stream)
{
  const float* x1   = (const float*)d_in[0];
  const float* x2   = (const float*)d_in[1];
  const int*   neigh= (const int*)d_in[2];
  const int*   top  = (const int*)d_in[3];
  const int*   down = (const int*)d_in[4];
  const float* upW  = (const float*)d_in[5];
  const float* upb  = (const float*)d_in[6];
  const float* c1W  = (const float*)d_in[7];
  const float* c1b  = (const float*)d_in[8];
  const float* g1   = (const float*)d_in[9];
  const float* b1   = (const float*)d_in[10];
  const float* c2W  = (const float*)d_in[11];
  const float* c2b  = (const float*)d_in[12];
  const float* g2   = (const float*)d_in[13];
  const float* b2   = (const float*)d_in[14];

  // d_out (83,887,104 B) staging plan:
  //   [0, 83886080)  xcat bf16 [B*NH][128]: cols 0:64 = xup, 64:128 = bf16(x2)
  //   (x1 read fp32 directly by the up-GEMM, once — no cvt pass, no re-read.)
  //   xcat dead after conv1 -> out fp32 reuses d_out.
  // ws: y1 bf16 [B*NH][64] = 41,943,552 (h bf16 36.7MB overlays it in phase 1).
  //   Gated tail (+17,408 B): st1 (8,704) + st2 (8,704).
  // Weights read fp32 directly from d_in inside the GEMMs (no Wt staging room).
  char* dob = (char*)d_out;
  ushort_t* xcat = (ushort_t*)dob;
  float*    outb = (float*)d_out;
  ushort_t* hbuf = (ushort_t*)d_ws;
  ushort_t* ybuf = (ushort_t*)d_ws;

  const bool gated = ws_size >= (size_t)(41943552 + 17408);
  float* st1 = gated ? (float*)((char*)d_ws + 41943552) : (float*)d_out;
  float* st2 = gated ? (float*)((char*)d_ws + 41943552 + 8704) : (float*)d_ws;

  if (gated) zero_kernel<<<17, 256, 0, stream>>>(st1, 4352);  // st1+st2 adjacent

  // Phase 1 — per batch: h = x1(fp32) @ upW + upb (all 7 n-tiles per block);
  //           xup + bf16(x2) -> xcat
  for (int b = 0; b < 2; ++b) {
    gemm_conv<0, false><<<dim3(1, 161), 512, 0, stream>>>(
        (const ushort_t*)(x1 + (size_t)b * M_UP * 128), nullptr, upW, upb,
        hbuf, nullptr, M_UP, 448);
    build_xup_x2_kernel<<<10241, 256, 0, stream>>>(
        hbuf, top, down, x2 + (size_t)b * NH * 64,
        xcat + (size_t)b * NH * 128, (long long)NH * 16);
  }

  // Phase 2 — y1 = meshconv1(xcat) -> ws (+ fused BN1 stats if gated)
  if (gated) {
    gemm_conv<1, true><<<dim3(1, 1281), 512, 0, stream>>>(
        xcat, neigh, c1W, c1b, ybuf, st1, M_CV, 64);
  } else {
    gemm_conv<1, false><<<dim3(1, 1281), 512, 0, stream>>>(
        xcat, neigh, c1W, c1b, ybuf, nullptr, M_CV, 64);
    zero_kernel<<<9, 256, 0, stream>>>(st1, 2176);     // xcat dead now
    stats_bf16_kernel<<<2048, 256, 0, stream>>>(ybuf, st1, M_CV);
  }
  finalize_kernel<<<1, 64, 0, stream>>>(st1, g1, b1);
  bnl_kernel<false><<<10241, 256, 0, stream>>>(ybuf, st1 + 2048, 2621472LL);

  // Phase 3 — out = meshconv2(y1) -> d_out fp32 (+ fused BN2 stats if gated)
  if (gated) {
    gemm_conv<2, true><<<dim3(1, 1281), 512, 0, stream>>>(
        ybuf, neigh, c2W, c2b, outb, st2, M_CV, 64);
  } else {
    gemm_conv<2, false><<<dim3(1, 1281), 512, 0, stream>>>(
        ybuf, neigh, c2W, c2b, outb, nullptr, M_CV, 64);
    zero_kernel<<<9, 256, 0, stream>>>(st2, 2176);     // y1 dead now
    stats_f32_kernel<<<2048, 256, 0, stream>>>(outb, st2, M_CV);
  }
  finalize_kernel<<<1, 64, 0, stream>>>(st2, g2, b2);
  bnl_kernel<true><<<20481, 256, 0, stream>>>(outb, st2 + 2048, 5242944LL);
}

// Round 10
// 513.057 us; speedup vs baseline: 1.0294x; 1.0294x over previous
//
#include <hip/hip_runtime.h>
#include <stdint.h>

// Problem constants (B=2, Nr=40962, in_ch=128, out_ch=64). FP32 I/O.
#define NR     40962
#define NH     163842      // 4*NR-6
#define NR7    286734      // NR*7
#define M_UP   40962
#define M_CV   327684      // B*NH
#define BN_EPS 1e-5f
#define SLOPE  0.2f

typedef __attribute__((ext_vector_type(8))) short  short8;
typedef __attribute__((ext_vector_type(4))) float  f32x4;
typedef unsigned short ushort_t;

__device__ __forceinline__ ushort_t f2bf(float f) {
  union { float f; uint32_t u; } v; v.f = f;
  uint32_t r = v.u + 0x7fffu + ((v.u >> 16) & 1u);  // RNE
  return (ushort_t)(r >> 16);
}
__device__ __forceinline__ float bf2f(ushort_t h) {
  union { uint32_t u; float f; } v; v.u = ((uint32_t)h) << 16;
  return v.f;
}
__device__ __forceinline__ int clampi(int v, int hi) {
  v = v < 0 ? 0 : v;
  return v >= hi ? hi - 1 : v;
}

// ---------------------------------------------------------------------------
// Gather-GEMM, 256x64 tile, 8 waves (512 thr), 32 rows/wave.  (R6 config —
// session-best total 517 µs; conv1 signature 122 µs / FETCH 274 MB / zero
// spill, reproduced across runs. Six structural variants all land at the
// same 2.45-3.03 TB/s random-gather fabric rate: this is the HW plateau.)
// A: global->VGPR gather (16B/lane = exact MFMA fragment), 4-slot ring,
//    barrier-free K-loop, compiler-counted per-wave vmcnt.
// B: staged to LDS ONCE per stage (KHALF k), rows padded to KHALF+8 elems
//    (912B stride) -> ds_read_b128 octets balanced across bank groups.
// Register plan: ~64 arch VGPR + AGPR parking (unified file) — no scratch.
// WRITE_SIZE ~53MB (conv1) is the spill tripwire.
// MODE 0: dense A bf16 [M][128], K=128 (up-GEMM), out bf16 stride NW.
// MODE 1: conv1 gather, ch->(j=ch>>1, half=ch&1), row=xcat[idx][128], out bf16.
// MODE 2: conv2 gather, j=ch, row=y1[idx][64], out fp32.
// FSTATS: fused per-channel sum/sumsq -> statsPart[16 slices][128].
// ---------------------------------------------------------------------------
template<int MODE, int KHALF, int NSTAGE, int NCH, bool FSTATS>
__global__ __launch_bounds__(512, 2) void gemm_conv(
    const ushort_t* __restrict__ Asrc,
    const int*      __restrict__ neigh,
    const float*    __restrict__ Wf,     // fp32 [K][NW]
    const float*    __restrict__ bias,
    void*           __restrict__ OutV,
    float*          __restrict__ statsPart,
    int M, int NW)
{
  constexpr int RS = KHALF + 8;          // padded row stride (elems)
  __shared__ __align__(16) ushort_t Bs[64 * RS];

  const int tid  = threadIdx.x;
  const int wv   = tid >> 6;             // 0..7
  const int lane = tid & 63;
  const int r16  = lane & 15;
  const int q    = lane >> 4;
  const int mTile = blockIdx.y * 256;
  const int nTile = blockIdx.x * 64;
  constexpr int ROWE = (MODE == 2) ? 64 : 128;   // A row length (elems)

  // Gather row indices: 2 row-groups x 7 neighbor slots, per-lane registers.
  int idx[2][7];
  if constexpr (MODE != 0) {
#pragma unroll
    for (int rg = 0; rg < 2; ++rg) {
      int r = mTile + wv * 32 + rg * 16 + r16;
      if (r >= M) r = M - 1;
      const int gb = (r >= NH) ? 1 : 0;
      const int gn = r - gb * NH;
#pragma unroll
      for (int j = 0; j < 7; ++j)
        idx[rg][j] = gb * NH + clampi(neigh[gn * 7 + j], NH);
    }
  }

  f32x4 acc[2][4];
#pragma unroll
  for (int a = 0; a < 2; ++a)
#pragma unroll
    for (int i = 0; i < 4; ++i) acc[a][i] = (f32x4){0.f, 0.f, 0.f, 0.f};

  short8 areg[4][2][2];   // [ringslot][rowgroup][ks] — statically indexed

  auto loadA = [&](int slot, int ch) {
    if constexpr (MODE == 0) {
#pragma unroll
      for (int rg = 0; rg < 2; ++rg) {
        int r = mTile + wv * 32 + rg * 16 + r16;
        if (r >= M) r = M - 1;
        const ushort_t* base = Asrc + (size_t)r * 128 + ch * 64 + q * 8;
        areg[slot][rg][0] = *(const short8*)(base);
        areg[slot][rg][1] = *(const short8*)(base + 32);
      }
    } else {
      const int j  = (MODE == 1) ? (ch >> 1) : ch;
      const int cb = (MODE == 1) ? ((ch & 1) << 6) : 0;
#pragma unroll
      for (int rg = 0; rg < 2; ++rg) {
        const ushort_t* base = Asrc + (size_t)idx[rg][j] * ROWE + cb + q * 8;
        areg[slot][rg][0] = *(const short8*)(base);
        areg[slot][rg][1] = *(const short8*)(base + 32);
      }
    }
  };

  // Stage B: W fp32 [K][NW] -> Bs[n][RS] bf16. Thread: n = tid&63, covers
  // 8-elem k-slots strided by 8 subgroups. Coalesced per-k (lanes n=0..63
  // read 256B rows); write octets balanced across bank groups (RS pad).
  auto stageB = [&](int s) {
    const int n   = tid & 63;
    const int sub = tid >> 6;            // 0..7
    for (int slot = sub; slot < KHALF / 8; slot += 8) {
      const int kg = s * KHALF + slot * 8;
      float f[8];
#pragma unroll
      for (int u = 0; u < 8; ++u)
        f[u] = Wf[(size_t)(kg + u) * NW + nTile + n];
      short8 v;
#pragma unroll
      for (int u = 0; u < 8; ++u) v[u] = (short)f2bf(f[u]);
      *(short8*)&Bs[n * RS + slot * 8] = v;
    }
  };

  auto compute = [&](int slot, int chLoc) {
#pragma unroll
    for (int ks = 0; ks < 2; ++ks) {
      const int kk = chLoc * 64 + ks * 32 + q * 8;
#pragma unroll
      for (int ct = 0; ct < 4; ++ct) {
        const short8 b = *(const short8*)&Bs[(ct * 16 + r16) * RS + kk];
#pragma unroll
        for (int rg = 0; rg < 2; ++rg)
          acc[rg][ct] = __builtin_amdgcn_mfma_f32_16x16x32_bf16(
              areg[slot][rg][ks], b, acc[rg][ct], 0, 0, 0);
      }
    }
  };

  // Prologue: 3 chunks of A in flight under the whole B-staging.
  loadA(0, 0);
  if constexpr (NCH > 1) loadA(1, 1);
  if constexpr (NCH > 2) loadA(2, 2);
  stageB(0);
  __syncthreads();

#pragma unroll
  for (int s = 0; s < NSTAGE; ++s) {
    if (s > 0) {
      __syncthreads();    // all waves done reading previous stage's Bs
      stageB(s);
      __syncthreads();
    }
#pragma unroll
    for (int chLoc = 0; chLoc < KHALF / 64; ++chLoc) {
      const int ch = s * (KHALF / 64) + chLoc;
      if (ch + 3 < NCH) loadA((ch + 3) % 4, ch + 3);
      compute(ch % 4, chLoc);
    }
  }

  // epilogue: C/D layout col=lane&15, row=(lane>>4)*4+reg
  float s1a[4] = {0.f, 0.f, 0.f, 0.f};
  float s2a[4] = {0.f, 0.f, 0.f, 0.f};
#pragma unroll
  for (int ct = 0; ct < 4; ++ct) {
    const int colg = nTile + ct * 16 + r16;
    const float bv = bias[colg];
#pragma unroll
    for (int rg = 0; rg < 2; ++rg) {
#pragma unroll
      for (int i = 0; i < 4; ++i) {
        const int rowg = mTile + wv * 32 + rg * 16 + q * 4 + i;
        const float y = acc[rg][ct][i] + bv;
        if (rowg < M) {
          if constexpr (MODE == 2)
            ((float*)OutV)[(size_t)rowg * NW + colg] = y;
          else
            ((ushort_t*)OutV)[(size_t)rowg * NW + colg] = f2bf(y);
          if constexpr (FSTATS) { s1a[ct] += y; s2a[ct] += y * y; }
        }
      }
    }
  }

  if constexpr (FSTATS) {
    __syncthreads();                     // all Bs reads done; reuse as scratch
    float* Sred  = (float*)&Bs[0];       // [8 waves][64 ch]
    float* S2red = Sred + 512;
#pragma unroll
    for (int ct = 0; ct < 4; ++ct) {
      float v = s1a[ct], w = s2a[ct];
      v += __shfl_xor(v, 16, 64); v += __shfl_xor(v, 32, 64);
      w += __shfl_xor(w, 16, 64); w += __shfl_xor(w, 32, 64);
      if (q == 0) {
        Sred[wv * 64 + ct * 16 + r16]  = v;
        S2red[wv * 64 + ct * 16 + r16] = w;
      }
    }
    __syncthreads();
    if (tid < 64) {
      float v = 0.f, w = 0.f;
#pragma unroll
      for (int i = 0; i < 8; ++i) {
        v += Sred[i * 64 + tid];
        w += S2red[i * 64 + tid];
      }
      float* p = statsPart + (size_t)(blockIdx.y & 15) * 128;
      atomicAdd(&p[tid], v);
      atomicAdd(&p[64 + tid], w);
    }
  }
}

// ---------------------------------------------------------------------------
// Per batch: units [0, NH*8) build xup into LOW 64 channels of xcat rows;
// units [NH*8, NH*16) convert x2 (this batch) into HIGH 64 channels.
// ---------------------------------------------------------------------------
__global__ __launch_bounds__(256) void build_xup_x2_kernel(
    const ushort_t* __restrict__ h, const int* __restrict__ top,
    const int* __restrict__ down, const float* __restrict__ x2b,
    ushort_t* __restrict__ xcatB, long long total)
{
  const long long gid = (long long)blockIdx.x * 256 + threadIdx.x;
  if (gid >= total) return;
  if (gid < (long long)NH * 8) {
    const int n  = (int)(gid >> 3);
    const int c0 = (int)(gid & 7) * 8;
    short8 v;
    if (n < NR) {
      const int idx = clampi(top[n], NR7);
      v = *(const short8*)(h + (size_t)idx * 64 + c0);
    } else {
      const int d  = n - NR;
      const int i0 = clampi(down[d * 2], NR7);
      const int i1 = clampi(down[d * 2 + 1], NR7);
      short8 u0 = *(const short8*)(h + (size_t)i0 * 64 + c0);
      short8 u1 = *(const short8*)(h + (size_t)i1 * 64 + c0);
#pragma unroll
      for (int i = 0; i < 8; ++i)
        v[i] = (short)f2bf(0.5f * (bf2f((ushort_t)u0[i]) + bf2f((ushort_t)u1[i])));
    }
    *(short8*)(xcatB + (size_t)n * 128 + c0) = v;
  } else {
    const long long g2 = gid - (long long)NH * 8;
    const int n  = (int)(g2 >> 3);
    const int c0 = (int)(g2 & 7) * 8;
    const f32x4 f0 = *(const f32x4*)(x2b + (size_t)n * 64 + c0);
    const f32x4 f1 = *(const f32x4*)(x2b + (size_t)n * 64 + c0 + 4);
    short8 v;
#pragma unroll
    for (int i = 0; i < 4; ++i) {
      v[i]     = (short)f2bf(f0[i]);
      v[i + 4] = (short)f2bf(f1[i]);
    }
    *(short8*)(xcatB + (size_t)n * 128 + 64 + c0) = v;
  }
}

// x1 fp32 -> bf16 dense [40962][128]
__global__ __launch_bounds__(256) void cvt_bf_kernel(
    const float* __restrict__ src, ushort_t* __restrict__ dst, long long n8)
{
  const long long gid = (long long)blockIdx.x * 256 + threadIdx.x;
  if (gid >= n8) return;
  const f32x4 f0 = *(const f32x4*)(src + gid * 8);
  const f32x4 f1 = *(const f32x4*)(src + gid * 8 + 4);
  short8 v;
#pragma unroll
  for (int i = 0; i < 4; ++i) {
    v[i]     = (short)f2bf(f0[i]);
    v[i + 4] = (short)f2bf(f1[i]);
  }
  *(short8*)(dst + gid * 8) = v;
}

__global__ __launch_bounds__(256) void zero_kernel(float* __restrict__ p, int n) {
  const int gid = blockIdx.x * 256 + threadIdx.x;
  if (gid < n) p[gid] = 0.f;
}

// Fallback stats over fp32 buffer -> 16 partial slices
__global__ __launch_bounds__(256) void stats_f32_kernel(
    const float* __restrict__ buf, float* __restrict__ part, int rows)
{
  const int tid = threadIdx.x;
  const int c   = tid & 63;
  const int rl  = tid >> 6;
  float s = 0.f, s2 = 0.f;
  for (int r = blockIdx.x * 4 + rl; r < rows; r += gridDim.x * 4) {
    const float v = buf[(size_t)r * 64 + c];
    s += v; s2 += v * v;
  }
  __shared__ float sh[2][256];
  sh[0][tid] = s; sh[1][tid] = s2;
  __syncthreads();
  if (tid < 64) {
#pragma unroll
    for (int i = 1; i < 4; ++i) { s += sh[0][tid + 64 * i]; s2 += sh[1][tid + 64 * i]; }
    float* p = part + (size_t)(blockIdx.x & 15) * 128;
    atomicAdd(&p[c], s);
    atomicAdd(&p[64 + c], s2);
  }
}

// Fallback stats over bf16 buffer -> 16 partial slices
__global__ __launch_bounds__(256) void stats_bf16_kernel(
    const ushort_t* __restrict__ buf, float* __restrict__ part, int rows)
{
  const int tid = threadIdx.x;
  const int c   = tid & 63;
  const int rl  = tid >> 6;
  float s = 0.f, s2 = 0.f;
  for (int r = blockIdx.x * 4 + rl; r < rows; r += gridDim.x * 4) {
    const float v = bf2f(buf[(size_t)r * 64 + c]);
    s += v; s2 += v * v;
  }
  __shared__ float sh[2][256];
  sh[0][tid] = s; sh[1][tid] = s2;
  __syncthreads();
  if (tid < 64) {
#pragma unroll
    for (int i = 1; i < 4; ++i) { s += sh[0][tid + 64 * i]; s2 += sh[1][tid + 64 * i]; }
    float* p = part + (size_t)(blockIdx.x & 15) * 128;
    atomicAdd(&p[c], s);
    atomicAdd(&p[64 + c], s2);
  }
}

// Reduce 16 partial slices -> final [sc[64] | sh[64]] at part+2048
__global__ void finalize_kernel(float* __restrict__ part,
                                const float* __restrict__ gamma,
                                const float* __restrict__ beta)
{
  const int c = threadIdx.x;  // 64
  float s = 0.f, s2 = 0.f;
  for (int i = 0; i < 16; ++i) { s += part[i * 128 + c]; s2 += part[i * 128 + 64 + c]; }
  const float invN = 1.0f / (float)M_CV;
  const float mean = s * invN;
  float var = fmaxf(s2 * invN - mean * mean, 0.f);
  const float sc = gamma[c] * rsqrtf(var + BN_EPS);
  float* fin = part + 2048;
  fin[c] = sc;
  fin[64 + c] = beta[c] - mean * sc;
}

// In-place y = lrelu(v*sc[c] + sh[c]); fin = [sc[64] | sh[64]]
template<bool F32>
__global__ __launch_bounds__(256) void bnl_kernel(
    void* __restrict__ bufV, const float* __restrict__ fin, long long nvec)
{
  const long long gid = (long long)blockIdx.x * 256 + threadIdx.x;
  if (gid >= nvec) return;
  if constexpr (F32) {
    float* buf = (float*)bufV;
    const int c0 = (int)((gid * 4) & 63);
    f32x4 v = *(f32x4*)(buf + gid * 4);
#pragma unroll
    for (int i = 0; i < 4; ++i) {
      const float y = v[i] * fin[c0 + i] + fin[64 + c0 + i];
      v[i] = (y >= 0.f) ? y : SLOPE * y;
    }
    *(f32x4*)(buf + gid * 4) = v;
  } else {
    ushort_t* buf = (ushort_t*)bufV;
    const int c0 = (int)((gid * 8) & 63);
    short8 v = *(short8*)(buf + gid * 8);
#pragma unroll
    for (int i = 0; i < 8; ++i) {
      float y = bf2f((ushort_t)v[i]) * fin[c0 + i] + fin[64 + c0 + i];
      y = (y >= 0.f) ? y : SLOPE * y;
      v[i] = (short)f2bf(y);
    }
    *(short8*)(buf + gid * 8) = v;
  }
}

// ---------------------------------------------------------------------------
extern "C" void kernel_launch(void* const* d_in, const int* in_sizes, int n_in,
                              void* d_out, int out_size, void* d_ws, size_t ws_size,
                              hipStream_t stream)
{
  const float* x1   = (const float*)d_in[0];
  const float* x2   = (const float*)d_in[1];
  const int*   neigh= (const int*)d_in[2];
  const int*   top  = (const int*)d_in[3];
  const int*   down = (const int*)d_in[4];
  const float* upW  = (const float*)d_in[5];
  const float* upb  = (const float*)d_in[6];
  const float* c1W  = (const float*)d_in[7];
  const float* c1b  = (const float*)d_in[8];
  const float* g1   = (const float*)d_in[9];
  const float* b1   = (const float*)d_in[10];
  const float* c2W  = (const float*)d_in[11];
  const float* c2b  = (const float*)d_in[12];
  const float* g2   = (const float*)d_in[13];
  const float* b2   = (const float*)d_in[14];

  // d_out (83,887,104 B) staging plan:
  //   [0, 83886080)  xcat bf16 [B*NH][128]: cols 0:64 = xup, 64:128 = bf16(x2)
  //   x1bf (10,486,272 B) overlays the start of batch-b's xcat region; dead
  //   before build_xup_x2 writes there (strictly sequential stream).
  //   xcat dead after conv1 -> out fp32 reuses d_out.
  // ws: y1 bf16 [B*NH][64] = 41,943,552 (h bf16 36.7MB overlays it in phase 1).
  //   Gated tail (+17,408 B): st1 (8,704) + st2 (8,704).
  // Weights read fp32 directly from d_in inside the GEMMs (no Wt staging room).
  char* dob = (char*)d_out;
  ushort_t* xcat = (ushort_t*)dob;
  float*    outb = (float*)d_out;
  ushort_t* hbuf = (ushort_t*)d_ws;
  ushort_t* ybuf = (ushort_t*)d_ws;

  const bool gated = ws_size >= (size_t)(41943552 + 17408);
  float* st1 = gated ? (float*)((char*)d_ws + 41943552) : (float*)d_out;
  float* st2 = gated ? (float*)((char*)d_ws + 41943552 + 8704) : (float*)d_ws;

  if (gated) zero_kernel<<<17, 256, 0, stream>>>(st1, 4352);  // st1+st2 adjacent

  // Phase 1 — per batch: x1->bf16 (overlay); h = x1bf @ upW + upb;
  //           xup + bf16(x2) -> xcat (merged kernel)
  for (int b = 0; b < 2; ++b) {
    ushort_t* x1bf = xcat + (size_t)b * NH * 128;
    cvt_bf_kernel<<<2561, 256, 0, stream>>>(x1 + (size_t)b * M_UP * 128,
                                            x1bf, 655392LL);
    gemm_conv<0, 128, 1, 2, false><<<dim3(7, 161), 512, 0, stream>>>(
        x1bf, nullptr, upW, upb, hbuf, nullptr, M_UP, 448);
    build_xup_x2_kernel<<<10241, 256, 0, stream>>>(
        hbuf, top, down, x2 + (size_t)b * NH * 64,
        xcat + (size_t)b * NH * 128, (long long)NH * 16);
  }

  // Phase 2 — y1 = meshconv1(xcat) -> ws (+ fused BN1 stats if gated)
  if (gated) {
    gemm_conv<1, 448, 2, 14, true><<<dim3(1, 1281), 512, 0, stream>>>(
        xcat, neigh, c1W, c1b, ybuf, st1, M_CV, 64);
  } else {
    gemm_conv<1, 448, 2, 14, false><<<dim3(1, 1281), 512, 0, stream>>>(
        xcat, neigh, c1W, c1b, ybuf, nullptr, M_CV, 64);
    zero_kernel<<<9, 256, 0, stream>>>(st1, 2176);     // xcat dead now
    stats_bf16_kernel<<<2048, 256, 0, stream>>>(ybuf, st1, M_CV);
  }
  finalize_kernel<<<1, 64, 0, stream>>>(st1, g1, b1);
  bnl_kernel<false><<<10241, 256, 0, stream>>>(ybuf, st1 + 2048, 2621472LL);

  // Phase 3 — out = meshconv2(y1) -> d_out fp32 (+ fused BN2 stats if gated)
  if (gated) {
    gemm_conv<2, 448, 1, 7, true><<<dim3(1, 1281), 512, 0, stream>>>(
        ybuf, neigh, c2W, c2b, outb, st2, M_CV, 64);
  } else {
    gemm_conv<2, 448, 1, 7, false><<<dim3(1, 1281), 512, 0, stream>>>(
        ybuf, neigh, c2W, c2b, outb, nullptr, M_CV, 64);
    zero_kernel<<<9, 256, 0, stream>>>(st2, 2176);     // y1 dead now
    stats_f32_kernel<<<2048, 256, 0, stream>>>(outb, st2, M_CV);
  }
  finalize_kernel<<<1, 64, 0, stream>>>(st2, g2, b2);
  bnl_kernel<true><<<20481, 256, 0, stream>>>(outb, st2 + 2048, 5242944LL);
}